// Round 1
// baseline (582.412 us; speedup 1.0000x reference)
//
#include <hip/hip_runtime.h>
#include <hip/hip_bf16.h>

#define N 8192
#define D 128
#define INV_T 14.285714285714286f   // 1/0.07

typedef __bf16 v8bf __attribute__((ext_vector_type(8)));
typedef float  v4f  __attribute__((ext_vector_type(4)));

// ---------------- Kernel 1: row-normalize fp32 -> bf16 ----------------
// one wave (64 lanes) per row, 2 floats per lane
__global__ __launch_bounds__(256) void normalize_kernel(
    const float* __restrict__ f, __bf16* __restrict__ out)
{
    int gwave = (blockIdx.x * blockDim.x + threadIdx.x) >> 6;  // row id
    int lane  = threadIdx.x & 63;
    const float2 v = *reinterpret_cast<const float2*>(f + (size_t)gwave * D + lane * 2);
    float ss = v.x * v.x + v.y * v.y;
    #pragma unroll
    for (int m = 32; m; m >>= 1) ss += __shfl_xor(ss, m);
    float norm = fmaxf(sqrtf(ss), 1e-8f);
    float inv  = 1.0f / norm;
    __bf16* o = out + (size_t)gwave * D + lane * 2;
    o[0] = (__bf16)(v.x * inv);
    o[1] = (__bf16)(v.y * inv);
}

// ---------------- Kernel 2: fused Gram + exp + masked row-sums ----------------
// 128x128 tile per block, 4 waves in 2x2, each wave does 64x64 via 4x4 MFMA frags.
// Fragments loaded directly from global (fn = 2MB, L2-resident). Masks streamed.
__global__ __launch_bounds__(256) void supcon_main(
    const __bf16* __restrict__ F,
    const int* __restrict__ pmask, const int* __restrict__ nmask,
    float* __restrict__ pos, float* __restrict__ neg)
{
    const int tid  = threadIdx.x;
    const int lane = tid & 63;
    const int wid  = tid >> 6;       // 0..3
    const int wr   = wid >> 1, wc = wid & 1;
    const int i0   = blockIdx.y * 128 + wr * 64;
    const int j0   = blockIdx.x * 128 + wc * 64;
    const int r    = lane & 15;      // col within 16x16 fragment (C), row idx for A/B frags
    const int q    = lane >> 4;      // 0..3 : k-group for A/B, row-group for C

    v4f acc[4][4];
    #pragma unroll
    for (int m = 0; m < 4; ++m)
        #pragma unroll
        for (int n = 0; n < 4; ++n) acc[m][n] = (v4f)0.0f;

    // K = 128 = 4 MFMA K-steps of 32
    #pragma unroll
    for (int ks = 0; ks < 4; ++ks) {
        v8bf a[4], b[4];
        #pragma unroll
        for (int m = 0; m < 4; ++m)
            a[m] = *reinterpret_cast<const v8bf*>(F + (size_t)(i0 + m * 16 + r) * D + ks * 32 + q * 8);
        #pragma unroll
        for (int n = 0; n < 4; ++n)
            b[n] = *reinterpret_cast<const v8bf*>(F + (size_t)(j0 + n * 16 + r) * D + ks * 32 + q * 8);
        #pragma unroll
        for (int m = 0; m < 4; ++m)
            #pragma unroll
            for (int n = 0; n < 4; ++n)
                acc[m][n] = __builtin_amdgcn_mfma_f32_16x16x32_bf16(a[m], b[n], acc[m][n], 0, 0, 0);
    }

    // Epilogue: C layout col = lane&15 (=r), row = q*4 + v within each 16x16 frag.
    #pragma unroll
    for (int m = 0; m < 4; ++m) {
        #pragma unroll
        for (int v = 0; v < 4; ++v) {
            const int gi = i0 + m * 16 + q * 4 + v;
            const int* __restrict__ prow = pmask + (size_t)gi * N + j0 + r;
            const int* __restrict__ nrow = nmask + (size_t)gi * N + j0 + r;
            float p = 0.0f, g = 0.0f;
            #pragma unroll
            for (int n = 0; n < 4; ++n) {
                const int gj = j0 + n * 16 + r;
                int pm = prow[n * 16];
                int nm = nrow[n * 16];
                float s = acc[m][n][v];
                float e = __expf(s * INV_T);
                e = (gi != gj) ? e : 0.0f;
                p = fmaf((float)pm, e, p);
                g = fmaf((float)nm, e, g);
            }
            // reduce over the 16 lanes that share this row (they hold different cols)
            #pragma unroll
            for (int msk = 1; msk < 16; msk <<= 1) {
                p += __shfl_xor(p, msk);
                g += __shfl_xor(g, msk);
            }
            if (r == 0) {
                atomicAdd(&pos[gi], p);
                atomicAdd(&neg[gi], g);
            }
        }
    }
}

// ---------------- Kernel 3: loss = -mean(log(pos/(pos+neg))) ----------------
__global__ __launch_bounds__(1024) void finalize_kernel(
    const float* __restrict__ pos, const float* __restrict__ neg, float* __restrict__ out)
{
    __shared__ float sm[16];
    int tid = threadIdx.x;
    float acc = 0.0f;
    for (int i = tid; i < N; i += 1024) {
        float p = pos[i], g = neg[i];
        acc += logf(p / (p + g));
    }
    #pragma unroll
    for (int m = 32; m; m >>= 1) acc += __shfl_xor(acc, m);
    if ((tid & 63) == 0) sm[tid >> 6] = acc;
    __syncthreads();
    if (tid == 0) {
        float t = 0.0f;
        #pragma unroll
        for (int w = 0; w < 16; ++w) t += sm[w];
        out[0] = -t * (1.0f / (float)N);
    }
}

extern "C" void kernel_launch(void* const* d_in, const int* in_sizes, int n_in,
                              void* d_out, int out_size, void* d_ws, size_t ws_size,
                              hipStream_t stream) {
    const float* feat  = (const float*)d_in[0];
    const int*   pmask = (const int*)d_in[1];
    const int*   nmask = (const int*)d_in[2];
    float* out = (float*)d_out;

    char* ws = (char*)d_ws;
    __bf16* fnb = (__bf16*)ws;                              // 8192*128*2 = 2 MB
    float*  pos = (float*)(ws + (size_t)2 * 1024 * 1024);   // 32 KB
    float*  neg = pos + N;                                  // 32 KB

    hipMemsetAsync(pos, 0, 2 * N * sizeof(float), stream);

    normalize_kernel<<<dim3(N / 4), 256, 0, stream>>>(feat, fnb);

    dim3 grid(N / 128, N / 128);
    supcon_main<<<grid, 256, 0, stream>>>(fnb, pmask, nmask, pos, neg);

    finalize_kernel<<<1, 1024, 0, stream>>>(pos, neg, out);
}